// Round 1
// baseline (2857.709 us; speedup 1.0000x reference)
//
#include <hip/hip_runtime.h>

#define NGS 25
#define NGX 40
#define NGY 40
#define KK  64
#define NB2 4
#define NYY 1000
#define PTOT 625
#define PC  128
#define NCH 5
#define DAMP 0.01f

// ---------------- Kernel 1: per-tile Gram + A, then in-LDS SPD solve -> AG ----
__global__ __launch_bounds__(256) void k_gram_solve(
    const float* __restrict__ xin, const float* __restrict__ hist,
    float* __restrict__ AG)
{
  __shared__ float4 Vl4[KK * 32];       // swizzled: row r, block b4 = (p>>2)^(r&31)
  __shared__ float4 Xl4[NB2 * 32];      // plain
  __shared__ float  Gs[KK][KK + 5];     // augmented 64 x 69 (cols 64..67 = A^T)

  float* Vl = (float*)Vl4;
  float* Xl = (float*)Xl4;

  const int tile = blockIdx.x;
  const int gx = tile / NGY, gy = tile % NGY;
  const size_t base = (size_t)(gx * NGS) * NYY + (size_t)(gy * NGS);
  const int tid  = threadIdx.x;
  const int wave = tid >> 6;
  const int lane = tid & 63;
  const int br = lane >> 3, bc = lane & 7;   // 8x8 output block of G

  float acc[8][8];
  #pragma unroll
  for (int i = 0; i < 8; ++i)
    #pragma unroll
    for (int j = 0; j < 8; ++j) acc[i][j] = 0.f;
  float accA = 0.f;                      // A[c=wave][k=lane]

  for (int ch = 0; ch < NCH; ++ch) {
    const int p0 = ch * PC;
    // ---- load V chunk (zero-padded past 625), swizzled float4 layout
    for (int idx = tid; idx < KK * PC; idx += 256) {
      const int r  = idx >> 7;
      const int pp = idx & 127;
      const int p  = p0 + pp;
      float v = 0.f;
      if (p < PTOT) {
        const int px = p / NGS, py = p - px * NGS;
        v = hist[(size_t)r * 1000000 + base + (size_t)px * NYY + py];
      }
      const int b4 = (pp >> 2) ^ (r & 31);
      Vl[(r * 32 + b4) * 4 + (pp & 3)] = v;
    }
    // ---- load X chunk (plain)
    for (int idx = tid; idx < NB2 * PC; idx += 256) {
      const int c  = idx >> 7;
      const int pp = idx & 127;
      const int p  = p0 + pp;
      float v = 0.f;
      if (p < PTOT) {
        const int px = p / NGS, py = p - px * NGS;
        v = xin[(size_t)c * 1000000 + base + (size_t)px * NYY + py];
      }
      Xl[c * PC + pp] = v;
    }
    __syncthreads();

    // ---- G partial: wave g covers p4 in [8g, 8g+8)
    #pragma unroll
    for (int t = 0; t < 8; ++t) {
      const int p4 = wave * 8 + t;
      float4 a[8], b[8];
      #pragma unroll
      for (int i = 0; i < 8; ++i) {
        const int r = br * 8 + i;
        a[i] = Vl4[r * 32 + (p4 ^ (r & 31))];
      }
      #pragma unroll
      for (int j = 0; j < 8; ++j) {
        const int r = bc * 8 + j;
        b[j] = Vl4[r * 32 + (p4 ^ (r & 31))];
      }
      #pragma unroll
      for (int i = 0; i < 8; ++i)
        #pragma unroll
        for (int j = 0; j < 8; ++j)
          acc[i][j] += a[i].x*b[j].x + a[i].y*b[j].y + a[i].z*b[j].z + a[i].w*b[j].w;
    }
    // ---- A partial: c = wave, k = lane, all p4 (conflict-free: 32 distinct quads)
    #pragma unroll 8
    for (int p4 = 0; p4 < 32; ++p4) {
      const float4 v  = Vl4[lane * 32 + (p4 ^ (lane & 31))];
      const float4 xv = Xl4[wave * 32 + p4];
      accA += v.x*xv.x + v.y*xv.y + v.z*xv.z + v.w*xv.w;
    }
    __syncthreads();
  }

  // ---- reduce 4 wave-partials of G into Gs (+ damping)
  for (int g = 0; g < 4; ++g) {
    if (wave == g) {
      #pragma unroll
      for (int i = 0; i < 8; ++i)
        #pragma unroll
        for (int j = 0; j < 8; ++j) {
          const int r = br * 8 + i, cc = bc * 8 + j;
          if (g == 0) Gs[r][cc] = acc[i][j] + ((r == cc) ? DAMP : 0.f);
          else        Gs[r][cc] += acc[i][j];
        }
    }
    __syncthreads();
  }
  Gs[lane][KK + wave] = accA;   // augmented A^T
  __syncthreads();

  // ---- Gaussian elimination (no pivoting; damped SPD), 4 threads per row
  const int ei = tid >> 2, eq = tid & 3;
  for (int k = 0; k < KK; ++k) {
    __syncthreads();
    if (ei > k) {
      const float f = Gs[ei][k] / Gs[k][k];
      for (int j = k + 1 + ((eq - (k + 1)) & 3); j < KK + NB2; j += 4)
        Gs[ei][j] -= f * Gs[k][j];
    }
  }
  __syncthreads();

  // ---- back substitution: wave c solves RHS c; lane j holds x[j]
  {
    const int c = wave;
    float xr = 0.f;
    for (int i = KK - 1; i >= 0; --i) {
      float contrib = (lane > i) ? Gs[i][lane] * xr : 0.f;
      #pragma unroll
      for (int off = 1; off < 64; off <<= 1)
        contrib += __shfl_xor(contrib, off);
      const float xi = (Gs[i][KK + c] - contrib) / Gs[i][i];
      if (lane == i) xr = xi;
    }
    AG[(size_t)tile * 256 + c * 64 + lane] = xr;   // AG[c][k]
  }
}

// ---------------- Kernel 2: Y = AG * V, scatter to output ---------------------
__global__ __launch_bounds__(256) void k_project(
    const float* __restrict__ hist, const float* __restrict__ AG,
    float* __restrict__ out)
{
  __shared__ float ag[KK][NB2];   // ag[k][c]
  const int tile = blockIdx.x;
  const int gx = tile / NGY, gy = tile % NGY;
  const size_t base = (size_t)(gx * NGS) * NYY + (size_t)(gy * NGS);
  const int tid = threadIdx.x;
  {
    const int c = tid >> 6, k = tid & 63;
    ag[k][c] = AG[(size_t)tile * 256 + tid];   // AG[c][k] -> ag[k][c]
  }
  __syncthreads();

  const int p1 = tid, p2 = tid + 256, p3 = tid + 512;
  const int a1 = (p1 / NGS) * NYY + (p1 % NGS);
  const int a2 = (p2 / NGS) * NYY + (p2 % NGS);
  const bool has3 = (p3 < PTOT);
  const int a3 = has3 ? ((p3 / NGS) * NYY + (p3 % NGS)) : 0;

  float o1[4] = {0,0,0,0}, o2[4] = {0,0,0,0}, o3[4] = {0,0,0,0};
  const float4* ag4 = (const float4*)ag;

  #pragma unroll 4
  for (int k = 0; k < KK; ++k) {
    const size_t ko = (size_t)k * 1000000 + base;
    const float v1 = hist[ko + a1];
    const float v2 = hist[ko + a2];
    const float v3 = has3 ? hist[ko + a3] : 0.f;
    const float4 w = ag4[k];
    o1[0] += w.x * v1; o1[1] += w.y * v1; o1[2] += w.z * v1; o1[3] += w.w * v1;
    o2[0] += w.x * v2; o2[1] += w.y * v2; o2[2] += w.z * v2; o2[3] += w.w * v2;
    o3[0] += w.x * v3; o3[1] += w.y * v3; o3[2] += w.z * v3; o3[3] += w.w * v3;
  }

  out[(size_t)0 * 1000000 + base + a1] = o1[0];
  out[(size_t)1 * 1000000 + base + a1] = o1[1];
  out[(size_t)2 * 1000000 + base + a1] = o1[2];
  out[(size_t)3 * 1000000 + base + a1] = o1[3];
  out[(size_t)0 * 1000000 + base + a2] = o2[0];
  out[(size_t)1 * 1000000 + base + a2] = o2[1];
  out[(size_t)2 * 1000000 + base + a2] = o2[2];
  out[(size_t)3 * 1000000 + base + a2] = o2[3];
  if (has3) {
    out[(size_t)0 * 1000000 + base + a3] = o3[0];
    out[(size_t)1 * 1000000 + base + a3] = o3[1];
    out[(size_t)2 * 1000000 + base + a3] = o3[2];
    out[(size_t)3 * 1000000 + base + a3] = o3[3];
  }
}

extern "C" void kernel_launch(void* const* d_in, const int* in_sizes, int n_in,
                              void* d_out, int out_size, void* d_ws, size_t ws_size,
                              hipStream_t stream) {
  const float* xin  = (const float*)d_in[0];   // local_x  (1,4,1000,1000)
  const float* hist = (const float*)d_in[1];   // ms_history (1,16,4,1000,1000)
  float* out = (float*)d_out;
  float* AG  = (float*)d_ws;                   // 1600 * 256 floats = 1.6 MB

  k_gram_solve<<<NGX * NGY, 256, 0, stream>>>(xin, hist, AG);
  k_project  <<<NGX * NGY, 256, 0, stream>>>(hist, AG, out);
}

// Round 2
// 482.975 us; speedup vs baseline: 5.9169x; 5.9169x over previous
//
#include <hip/hip_runtime.h>

#define NGS 25
#define NGX 40
#define NGY 40
#define KK  64
#define NB2 4
#define NYY 1000
#define PTOT 625
#define PC  128
#define NCH 5
#define DAMP 0.01f

// ---------------- Kernel 1: per-tile Gram + A, then in-LDS SPD solve -> AG ----
// 256 threads = 16x16 grid of 4x4 register blocks of G; each thread integrates
// over ALL p (no cross-wave reduction). Gs aliases the V-tile LDS (V dead by then).
__global__ __launch_bounds__(256, 4) void k_gram_solve(
    const float* __restrict__ xin, const float* __restrict__ hist,
    float* __restrict__ AG)
{
  // 32 KB V (swizzled float4) + 2 KB X; Gs (64x69 = 17.7 KB) aliases V region.
  __shared__ __align__(16) float smemf[(32 * 1024 + 2 * 1024) / 4];
  float4* Vl4 = (float4*)smemf;
  float*  Vl  = smemf;
  float4* Xl4 = (float4*)(smemf + 8192);
  float*  Xl  = smemf + 8192;
  float (*Gs)[KK + 5] = (float (*)[KK + 5])smemf;

  const int tile = blockIdx.x;
  const int gx = tile / NGY, gy = tile % NGY;
  const size_t base = (size_t)(gx * NGS) * NYY + (size_t)(gy * NGS);
  const int tid  = threadIdx.x;
  const int wave = tid >> 6;
  const int lane = tid & 63;
  const int ti = tid >> 4;      // row-block 0..15
  const int tj = tid & 15;      // col-block 0..15

  float acc[4][4];
  #pragma unroll
  for (int i = 0; i < 4; ++i)
    #pragma unroll
    for (int j = 0; j < 4; ++j) acc[i][j] = 0.f;
  float accA = 0.f;             // A[c=wave][k=lane]

  for (int ch = 0; ch < NCH; ++ch) {
    const int p0 = ch * PC;
    // ---- load V chunk (zero-padded past 625), swizzled float4 layout
    for (int idx = tid; idx < KK * PC; idx += 256) {
      const int r  = idx >> 7;
      const int pp = idx & 127;
      const int p  = p0 + pp;
      float v = 0.f;
      if (p < PTOT) {
        const int px = p / NGS, py = p - px * NGS;
        v = hist[(size_t)r * 1000000 + base + (size_t)px * NYY + py];
      }
      const int b4 = (pp >> 2) ^ (r & 31);
      Vl[(r * 32 + b4) * 4 + (pp & 3)] = v;
    }
    // ---- load X chunk (plain)
    for (int idx = tid; idx < NB2 * PC; idx += 256) {
      const int c  = idx >> 7;
      const int pp = idx & 127;
      const int p  = p0 + pp;
      float v = 0.f;
      if (p < PTOT) {
        const int px = p / NGS, py = p - px * NGS;
        v = xin[(size_t)c * 1000000 + base + (size_t)px * NYY + py];
      }
      Xl[c * PC + pp] = v;
    }
    __syncthreads();

    // ---- G partial: each thread does its 4x4 block over all 32 quads
    #pragma unroll 2
    for (int p4 = 0; p4 < 32; ++p4) {
      float4 a[4], b[4];
      #pragma unroll
      for (int i = 0; i < 4; ++i) {
        const int r = ti * 4 + i;
        a[i] = Vl4[r * 32 + (p4 ^ (r & 31))];
      }
      #pragma unroll
      for (int j = 0; j < 4; ++j) {
        const int r = tj * 4 + j;
        b[j] = Vl4[r * 32 + (p4 ^ (r & 31))];
      }
      #pragma unroll
      for (int i = 0; i < 4; ++i)
        #pragma unroll
        for (int j = 0; j < 4; ++j)
          acc[i][j] += a[i].x*b[j].x + a[i].y*b[j].y + a[i].z*b[j].z + a[i].w*b[j].w;
    }
    // ---- A partial: c = wave, k = lane
    #pragma unroll 4
    for (int p4 = 0; p4 < 32; ++p4) {
      const float4 v  = Vl4[lane * 32 + (p4 ^ (lane & 31))];
      const float4 xv = Xl4[wave * 32 + p4];
      accA += v.x*xv.x + v.y*xv.y + v.z*xv.z + v.w*xv.w;
    }
    __syncthreads();
  }

  // ---- write G (+damping) into Gs (aliases dead V region; sync above guards)
  #pragma unroll
  for (int i = 0; i < 4; ++i)
    #pragma unroll
    for (int j = 0; j < 4; ++j) {
      const int r = ti * 4 + i, c = tj * 4 + j;
      Gs[r][c] = acc[i][j] + ((r == c) ? DAMP : 0.f);
    }
  __syncthreads();
  Gs[lane][KK + wave] = accA;   // augmented A^T
  __syncthreads();

  // ---- Gaussian elimination (no pivoting; damped SPD), 4 threads per row
  const int ei = tid >> 2, eq = tid & 3;
  for (int k = 0; k < KK; ++k) {
    __syncthreads();
    if (ei > k) {
      const float f = Gs[ei][k] / Gs[k][k];
      for (int j = k + 1 + ((eq - (k + 1)) & 3); j < KK + NB2; j += 4)
        Gs[ei][j] -= f * Gs[k][j];
    }
  }
  __syncthreads();

  // ---- back substitution: wave c solves RHS c; lane j holds x[j]
  {
    const int c = wave;
    float xr = 0.f;
    for (int i = KK - 1; i >= 0; --i) {
      float contrib = (lane > i) ? Gs[i][lane] * xr : 0.f;
      #pragma unroll
      for (int off = 1; off < 64; off <<= 1)
        contrib += __shfl_xor(contrib, off);
      const float xi = (Gs[i][KK + c] - contrib) / Gs[i][i];
      if (lane == i) xr = xi;
    }
    AG[(size_t)tile * 256 + c * 64 + lane] = xr;   // AG[c][k]
  }
}

// ---------------- Kernel 2: Y = AG * V, scatter to output ---------------------
__global__ __launch_bounds__(256) void k_project(
    const float* __restrict__ hist, const float* __restrict__ AG,
    float* __restrict__ out)
{
  __shared__ float ag[KK][NB2];   // ag[k][c]
  const int tile = blockIdx.x;
  const int gx = tile / NGY, gy = tile % NGY;
  const size_t base = (size_t)(gx * NGS) * NYY + (size_t)(gy * NGS);
  const int tid = threadIdx.x;
  {
    const int c = tid >> 6, k = tid & 63;
    ag[k][c] = AG[(size_t)tile * 256 + tid];   // AG[c][k] -> ag[k][c]
  }
  __syncthreads();

  const int p1 = tid, p2 = tid + 256, p3 = tid + 512;
  const int a1 = (p1 / NGS) * NYY + (p1 % NGS);
  const int a2 = (p2 / NGS) * NYY + (p2 % NGS);
  const bool has3 = (p3 < PTOT);
  const int a3 = has3 ? ((p3 / NGS) * NYY + (p3 % NGS)) : 0;

  float o1[4] = {0,0,0,0}, o2[4] = {0,0,0,0}, o3[4] = {0,0,0,0};
  const float4* ag4 = (const float4*)ag;

  #pragma unroll 4
  for (int k = 0; k < KK; ++k) {
    const size_t ko = (size_t)k * 1000000 + base;
    const float v1 = hist[ko + a1];
    const float v2 = hist[ko + a2];
    const float v3 = has3 ? hist[ko + a3] : 0.f;
    const float4 w = ag4[k];
    o1[0] += w.x * v1; o1[1] += w.y * v1; o1[2] += w.z * v1; o1[3] += w.w * v1;
    o2[0] += w.x * v2; o2[1] += w.y * v2; o2[2] += w.z * v2; o2[3] += w.w * v2;
    o3[0] += w.x * v3; o3[1] += w.y * v3; o3[2] += w.z * v3; o3[3] += w.w * v3;
  }

  out[(size_t)0 * 1000000 + base + a1] = o1[0];
  out[(size_t)1 * 1000000 + base + a1] = o1[1];
  out[(size_t)2 * 1000000 + base + a1] = o1[2];
  out[(size_t)3 * 1000000 + base + a1] = o1[3];
  out[(size_t)0 * 1000000 + base + a2] = o2[0];
  out[(size_t)1 * 1000000 + base + a2] = o2[1];
  out[(size_t)2 * 1000000 + base + a2] = o2[2];
  out[(size_t)3 * 1000000 + base + a2] = o2[3];
  if (has3) {
    out[(size_t)0 * 1000000 + base + a3] = o3[0];
    out[(size_t)1 * 1000000 + base + a3] = o3[1];
    out[(size_t)2 * 1000000 + base + a3] = o3[2];
    out[(size_t)3 * 1000000 + base + a3] = o3[3];
  }
}

extern "C" void kernel_launch(void* const* d_in, const int* in_sizes, int n_in,
                              void* d_out, int out_size, void* d_ws, size_t ws_size,
                              hipStream_t stream) {
  const float* xin  = (const float*)d_in[0];   // local_x  (1,4,1000,1000)
  const float* hist = (const float*)d_in[1];   // ms_history (1,16,4,1000,1000)
  float* out = (float*)d_out;
  float* AG  = (float*)d_ws;                   // 1600 * 256 floats = 1.6 MB

  k_gram_solve<<<NGX * NGY, 256, 0, stream>>>(xin, hist, AG);
  k_project  <<<NGX * NGY, 256, 0, stream>>>(hist, AG, out);
}

// Round 3
// 449.259 us; speedup vs baseline: 6.3609x; 1.0750x over previous
//
#include <hip/hip_runtime.h>

#define NGS 25
#define NGX 40
#define NGY 40
#define KK  64
#define NB2 4
#define NYY 1000
#define PTOT 625
#define PC  128
#define NCH 5
#define DAMP 0.01f

// float4-bank-group-aware swizzle: only (quad mod 8) determines the 4-bank
// group a b128 access hits, so XOR with (r>>2)&7 — distinguishes the 16 tj
// (b-reads), the 4 ti (a-reads), and spreads lane-reads uniformly.
#define SWZ(r) (((r) >> 2) & 7)

// ---------------- Kernel 1: per-tile Gram + A, then in-LDS SPD solve -> AG ----
__global__ __launch_bounds__(256, 4) void k_gram_solve(
    const float* __restrict__ xin, const float* __restrict__ hist,
    float* __restrict__ AG)
{
  // 32 KB V (swizzled float4) + 2 KB X; Gs (64x69 = 17.7 KB) aliases V region.
  __shared__ __align__(16) float smemf[(32 * 1024 + 2 * 1024) / 4];
  float4* Vl4 = (float4*)smemf;
  float*  Vl  = smemf;
  float4* Xl4 = (float4*)(smemf + 8192);
  float*  Xl  = smemf + 8192;
  float (*Gs)[KK + 5] = (float (*)[KK + 5])smemf;

  const int tile = blockIdx.x;
  const int gx = tile / NGY, gy = tile % NGY;
  const size_t base = (size_t)(gx * NGS) * NYY + (size_t)(gy * NGS);
  const int tid  = threadIdx.x;
  const int wave = tid >> 6;
  const int lane = tid & 63;
  const int ti = tid >> 4;      // row-block 0..15
  const int tj = tid & 15;      // col-block 0..15

  float acc[4][4];
  #pragma unroll
  for (int i = 0; i < 4; ++i)
    #pragma unroll
    for (int j = 0; j < 4; ++j) acc[i][j] = 0.f;
  float accA = 0.f;             // A[c=wave][k=lane]

  for (int ch = 0; ch < NCH; ++ch) {
    const int p0 = ch * PC;
    // ---- load V chunk (zero-padded past 625), swizzled float4 layout
    for (int idx = tid; idx < KK * PC; idx += 256) {
      const int r  = idx >> 7;
      const int pp = idx & 127;
      const int p  = p0 + pp;
      float v = 0.f;
      if (p < PTOT) {
        const int px = p / NGS, py = p - px * NGS;
        v = hist[(size_t)r * 1000000 + base + (size_t)px * NYY + py];
      }
      const int b4 = (pp >> 2) ^ SWZ(r);
      Vl[(r * 32 + b4) * 4 + (pp & 3)] = v;
    }
    // ---- load X chunk (plain)
    for (int idx = tid; idx < NB2 * PC; idx += 256) {
      const int c  = idx >> 7;
      const int pp = idx & 127;
      const int p  = p0 + pp;
      float v = 0.f;
      if (p < PTOT) {
        const int px = p / NGS, py = p - px * NGS;
        v = xin[(size_t)c * 1000000 + base + (size_t)px * NYY + py];
      }
      Xl[c * PC + pp] = v;
    }
    __syncthreads();

    // ---- G partial: each thread does its 4x4 block over all 32 quads
    #pragma unroll 2
    for (int p4 = 0; p4 < 32; ++p4) {
      float4 a[4], b[4];
      #pragma unroll
      for (int i = 0; i < 4; ++i) {
        const int r = ti * 4 + i;
        a[i] = Vl4[r * 32 + (p4 ^ SWZ(r))];
      }
      #pragma unroll
      for (int j = 0; j < 4; ++j) {
        const int r = tj * 4 + j;
        b[j] = Vl4[r * 32 + (p4 ^ SWZ(r))];
      }
      #pragma unroll
      for (int i = 0; i < 4; ++i)
        #pragma unroll
        for (int j = 0; j < 4; ++j)
          acc[i][j] += a[i].x*b[j].x + a[i].y*b[j].y + a[i].z*b[j].z + a[i].w*b[j].w;
    }
    // ---- A partial: c = wave, k = lane
    #pragma unroll 4
    for (int p4 = 0; p4 < 32; ++p4) {
      const float4 v  = Vl4[lane * 32 + (p4 ^ SWZ(lane))];
      const float4 xv = Xl4[wave * 32 + p4];
      accA += v.x*xv.x + v.y*xv.y + v.z*xv.z + v.w*xv.w;
    }
    __syncthreads();
  }

  // ---- write G (+damping) into Gs (aliases dead V region; sync above guards)
  #pragma unroll
  for (int i = 0; i < 4; ++i)
    #pragma unroll
    for (int j = 0; j < 4; ++j) {
      const int r = ti * 4 + i, c = tj * 4 + j;
      Gs[r][c] = acc[i][j] + ((r == c) ? DAMP : 0.f);
    }
  __syncthreads();
  Gs[lane][KK + wave] = accA;   // augmented A^T
  __syncthreads();

  // ---- Gaussian elimination (no pivoting; damped SPD), 4 threads per row
  const int ei = tid >> 2, eq = tid & 3;
  for (int k = 0; k < KK; ++k) {
    __syncthreads();
    if (ei > k) {
      const float f = Gs[ei][k] / Gs[k][k];
      for (int j = k + 1 + ((eq - (k + 1)) & 3); j < KK + NB2; j += 4)
        Gs[ei][j] -= f * Gs[k][j];
    }
  }
  __syncthreads();

  // ---- back substitution: wave c solves RHS c; lane j holds x[j]
  {
    const int c = wave;
    float xr = 0.f;
    for (int i = KK - 1; i >= 0; --i) {
      float contrib = (lane > i) ? Gs[i][lane] * xr : 0.f;
      #pragma unroll
      for (int off = 1; off < 64; off <<= 1)
        contrib += __shfl_xor(contrib, off);
      const float xi = (Gs[i][KK + c] - contrib) / Gs[i][i];
      if (lane == i) xr = xi;
    }
    AG[(size_t)tile * 256 + c * 64 + lane] = xr;   // AG[c][k]
  }
}

// ---------------- Kernel 2: Y = AG * V, scatter to output ---------------------
__global__ __launch_bounds__(256) void k_project(
    const float* __restrict__ hist, const float* __restrict__ AG,
    float* __restrict__ out)
{
  __shared__ float ag[KK][NB2];   // ag[k][c]
  const int tile = blockIdx.x;
  const int gx = tile / NGY, gy = tile % NGY;
  const size_t base = (size_t)(gx * NGS) * NYY + (size_t)(gy * NGS);
  const int tid = threadIdx.x;
  {
    const int c = tid >> 6, k = tid & 63;
    ag[k][c] = AG[(size_t)tile * 256 + tid];   // AG[c][k] -> ag[k][c]
  }
  __syncthreads();

  const int p1 = tid, p2 = tid + 256, p3 = tid + 512;
  const int a1 = (p1 / NGS) * NYY + (p1 % NGS);
  const int a2 = (p2 / NGS) * NYY + (p2 % NGS);
  const bool has3 = (p3 < PTOT);
  const int a3 = has3 ? ((p3 / NGS) * NYY + (p3 % NGS)) : 0;

  float o1[4] = {0,0,0,0}, o2[4] = {0,0,0,0}, o3[4] = {0,0,0,0};
  const float4* ag4 = (const float4*)ag;

  #pragma unroll 4
  for (int k = 0; k < KK; ++k) {
    const size_t ko = (size_t)k * 1000000 + base;
    const float v1 = hist[ko + a1];
    const float v2 = hist[ko + a2];
    const float v3 = has3 ? hist[ko + a3] : 0.f;
    const float4 w = ag4[k];
    o1[0] += w.x * v1; o1[1] += w.y * v1; o1[2] += w.z * v1; o1[3] += w.w * v1;
    o2[0] += w.x * v2; o2[1] += w.y * v2; o2[2] += w.z * v2; o2[3] += w.w * v2;
    o3[0] += w.x * v3; o3[1] += w.y * v3; o3[2] += w.z * v3; o3[3] += w.w * v3;
  }

  out[(size_t)0 * 1000000 + base + a1] = o1[0];
  out[(size_t)1 * 1000000 + base + a1] = o1[1];
  out[(size_t)2 * 1000000 + base + a1] = o1[2];
  out[(size_t)3 * 1000000 + base + a1] = o1[3];
  out[(size_t)0 * 1000000 + base + a2] = o2[0];
  out[(size_t)1 * 1000000 + base + a2] = o2[1];
  out[(size_t)2 * 1000000 + base + a2] = o2[2];
  out[(size_t)3 * 1000000 + base + a2] = o2[3];
  if (has3) {
    out[(size_t)0 * 1000000 + base + a3] = o3[0];
    out[(size_t)1 * 1000000 + base + a3] = o3[1];
    out[(size_t)2 * 1000000 + base + a3] = o3[2];
    out[(size_t)3 * 1000000 + base + a3] = o3[3];
  }
}

extern "C" void kernel_launch(void* const* d_in, const int* in_sizes, int n_in,
                              void* d_out, int out_size, void* d_ws, size_t ws_size,
                              hipStream_t stream) {
  const float* xin  = (const float*)d_in[0];   // local_x  (1,4,1000,1000)
  const float* hist = (const float*)d_in[1];   // ms_history (1,16,4,1000,1000)
  float* out = (float*)d_out;
  float* AG  = (float*)d_ws;                   // 1600 * 256 floats = 1.6 MB

  k_gram_solve<<<NGX * NGY, 256, 0, stream>>>(xin, hist, AG);
  k_project  <<<NGX * NGY, 256, 0, stream>>>(hist, AG, out);
}

// Round 4
// 389.935 us; speedup vs baseline: 7.3287x; 1.1521x over previous
//
#include <hip/hip_runtime.h>

#define NGS 25
#define NGX 40
#define NGY 40
#define KK  64
#define NB2 4
#define NYY 1000
#define PTOT 625
#define PC  128
#define NCH 5
#define DAMP 0.01f

typedef __attribute__((ext_vector_type(8))) short short8;
typedef __attribute__((ext_vector_type(4))) float f32x4;

__device__ __forceinline__ short bf16_rn(float x) {
  unsigned u = __float_as_uint(x);
  u = u + 0x7fffu + ((u >> 16) & 1u);
  return (short)(u >> 16);
}
__device__ __forceinline__ float bf16_tof(short s) {
  return __uint_as_float(((unsigned)(unsigned short)s) << 16);
}

// ---------------- Kernel 1: MFMA Gram (bf16 hi/lo split) + in-LDS solve ------
// LDS: two bf16 planes [80 rows][128 k] (rows 0..63 = V, 64..67 = X, 68..79 = 0),
// fragment-major with XOR swizzle: short offset = r*128 + ((k8 ^ (r&7))<<3) + (k&7).
// Wave w computes G rows [16w,16w+16) (4 tiles x 3 split-MFMAs per K-step) and
// the A-tile X·V_w^T. Gs (64x69 fp32) aliases the planes after the last read.
__global__ __launch_bounds__(256, 4) void k_gram_solve(
    const float* __restrict__ xin, const float* __restrict__ hist,
    float* __restrict__ AG)
{
  __shared__ __align__(16) short smem[2 * 80 * 128];   // 40 KB
  short* Vhi = smem;
  short* Vlo = smem + 80 * 128;
  float (*Gs)[KK + 5] = (float (*)[KK + 5])smem;       // aliases first 17.7 KB

  const int tile = blockIdx.x;
  const int gx = tile / NGY, gy = tile % NGY;
  const size_t base = (size_t)(gx * NGS) * NYY + (size_t)(gy * NGS);
  const int tid  = threadIdx.x;
  const int wave = tid >> 6;
  const int lane = tid & 63;
  const int u    = lane >> 4;     // k-group 0..3
  const int col  = lane & 15;

  // zero-pad rows 68..79 once (never re-written)
  for (int i = tid + 68 * 128; i < 80 * 128; i += 256) { Vhi[i] = 0; Vlo[i] = 0; }

  f32x4 accG[4];
  #pragma unroll
  for (int j = 0; j < 4; ++j) { accG[j].x = 0.f; accG[j].y = 0.f; accG[j].z = 0.f; accG[j].w = 0.f; }
  f32x4 accX; accX.x = 0.f; accX.y = 0.f; accX.z = 0.f; accX.w = 0.f;

  const int rA = 16 * wave + col;   // this wave's G row-block fragment row
  const int rX = KK + col;          // X block fragment row

  for (int ch = 0; ch < NCH; ++ch) {
    const int p0 = ch * PC;
    // ---- stage V (rows 0..63) + X (rows 64..67) as bf16 hi/lo, swizzled
    for (int idx = tid; idx < 68 * 128; idx += 256) {
      const int r = idx >> 7, pp = idx & 127;
      const int p = p0 + pp;
      float v = 0.f;
      if (p < PTOT) {
        const int px = p / NGS, py = p - px * NGS;
        const size_t a = base + (size_t)px * NYY + py;
        v = (r < KK) ? hist[(size_t)r * 1000000 + a]
                     : xin[(size_t)(r - KK) * 1000000 + a];
      }
      const short h = bf16_rn(v);
      const short l = bf16_rn(v - bf16_tof(h));
      const int off = r * 128 + ((((pp >> 3) ^ (r & 7)) << 3) | (pp & 7));
      Vhi[off] = h; Vlo[off] = l;
    }
    __syncthreads();

    // ---- 4 K-steps of 32 per chunk
    #pragma unroll
    for (int t = 0; t < 4; ++t) {
      const int k8 = t * 4 + u;
      #define FRG(P, r) (*(const short8*)&P[(r) * 128 + (((k8) ^ ((r) & 7)) << 3)])
      const short8 a_hi = FRG(Vhi, rA);
      const short8 a_lo = FRG(Vlo, rA);
      const short8 x_hi = FRG(Vhi, rX);
      const short8 x_lo = FRG(Vlo, rX);
      short8 b_hi[4], b_lo[4];
      #pragma unroll
      for (int s = 0; s < 4; ++s) {
        b_hi[s] = FRG(Vhi, 16 * s + col);
        b_lo[s] = FRG(Vlo, 16 * s + col);
      }
      #undef FRG
      #pragma unroll
      for (int j = 0; j < 4; ++j) {
        accG[j] = __builtin_amdgcn_mfma_f32_16x16x32_bf16(a_hi, b_hi[j], accG[j], 0, 0, 0);
        accG[j] = __builtin_amdgcn_mfma_f32_16x16x32_bf16(a_hi, b_lo[j], accG[j], 0, 0, 0);
        accG[j] = __builtin_amdgcn_mfma_f32_16x16x32_bf16(a_lo, b_hi[j], accG[j], 0, 0, 0);
      }
      // A-tile: X-block (A-operand) x V_w^T; B-frag of subtile w == a_hi/a_lo
      accX = __builtin_amdgcn_mfma_f32_16x16x32_bf16(x_hi, a_hi, accX, 0, 0, 0);
      accX = __builtin_amdgcn_mfma_f32_16x16x32_bf16(x_hi, a_lo, accX, 0, 0, 0);
      accX = __builtin_amdgcn_mfma_f32_16x16x32_bf16(x_lo, a_hi, accX, 0, 0, 0);
    }
    __syncthreads();
  }

  // ---- write G (+damping) into Gs (aliases planes; all reads done)
  const int row4 = u * 4;
  #pragma unroll
  for (int j = 0; j < 4; ++j)
    #pragma unroll
    for (int q = 0; q < 4; ++q) {
      const int gr = 16 * wave + row4 + q;
      const int gc = 16 * j + col;
      float g = (q == 0) ? accG[j].x : (q == 1) ? accG[j].y : (q == 2) ? accG[j].z : accG[j].w;
      Gs[gr][gc] = g + ((gr == gc) ? DAMP : 0.f);
    }
  // A^T into cols 64..67: lane<16 (u==0) holds channels q=0..3, k = 16*wave+lane
  if (lane < 16) {
    Gs[16 * wave + lane][KK + 0] = accX.x;
    Gs[16 * wave + lane][KK + 1] = accX.y;
    Gs[16 * wave + lane][KK + 2] = accX.z;
    Gs[16 * wave + lane][KK + 3] = accX.w;
  }
  __syncthreads();

  // ---- Gaussian elimination (no pivoting; damped SPD), 4 threads per row
  const int ei = tid >> 2, eq = tid & 3;
  for (int k = 0; k < KK; ++k) {
    __syncthreads();
    if (ei > k) {
      const float f = Gs[ei][k] / Gs[k][k];
      for (int j = k + 1 + ((eq - (k + 1)) & 3); j < KK + NB2; j += 4)
        Gs[ei][j] -= f * Gs[k][j];
    }
  }
  __syncthreads();

  // ---- back substitution: wave c solves RHS c; lane j holds x[j]
  {
    const int c = wave;
    float xr = 0.f;
    for (int i = KK - 1; i >= 0; --i) {
      float contrib = (lane > i) ? Gs[i][lane] * xr : 0.f;
      #pragma unroll
      for (int off = 1; off < 64; off <<= 1)
        contrib += __shfl_xor(contrib, off);
      const float xi = (Gs[i][KK + c] - contrib) / Gs[i][i];
      if (lane == i) xr = xi;
    }
    AG[(size_t)tile * 256 + c * 64 + lane] = xr;   // AG[c][k]
  }
}

// ---------------- Kernel 2: Y = AG * V, scatter to output ---------------------
__global__ __launch_bounds__(256) void k_project(
    const float* __restrict__ hist, const float* __restrict__ AG,
    float* __restrict__ out)
{
  __shared__ float ag[KK][NB2];   // ag[k][c]
  const int tile = blockIdx.x;
  const int gx = tile / NGY, gy = tile % NGY;
  const size_t base = (size_t)(gx * NGS) * NYY + (size_t)(gy * NGS);
  const int tid = threadIdx.x;
  {
    const int c = tid >> 6, k = tid & 63;
    ag[k][c] = AG[(size_t)tile * 256 + tid];   // AG[c][k] -> ag[k][c]
  }
  __syncthreads();

  const int p1 = tid, p2 = tid + 256, p3 = tid + 512;
  const int a1 = (p1 / NGS) * NYY + (p1 % NGS);
  const int a2 = (p2 / NGS) * NYY + (p2 % NGS);
  const bool has3 = (p3 < PTOT);
  const int a3 = has3 ? ((p3 / NGS) * NYY + (p3 % NGS)) : 0;

  float o1[4] = {0,0,0,0}, o2[4] = {0,0,0,0}, o3[4] = {0,0,0,0};
  const float4* ag4 = (const float4*)ag;

  #pragma unroll 4
  for (int k = 0; k < KK; ++k) {
    const size_t ko = (size_t)k * 1000000 + base;
    const float v1 = hist[ko + a1];
    const float v2 = hist[ko + a2];
    const float v3 = has3 ? hist[ko + a3] : 0.f;
    const float4 w = ag4[k];
    o1[0] += w.x * v1; o1[1] += w.y * v1; o1[2] += w.z * v1; o1[3] += w.w * v1;
    o2[0] += w.x * v2; o2[1] += w.y * v2; o2[2] += w.z * v2; o2[3] += w.w * v2;
    o3[0] += w.x * v3; o3[1] += w.y * v3; o3[2] += w.z * v3; o3[3] += w.w * v3;
  }

  out[(size_t)0 * 1000000 + base + a1] = o1[0];
  out[(size_t)1 * 1000000 + base + a1] = o1[1];
  out[(size_t)2 * 1000000 + base + a1] = o1[2];
  out[(size_t)3 * 1000000 + base + a1] = o1[3];
  out[(size_t)0 * 1000000 + base + a2] = o2[0];
  out[(size_t)1 * 1000000 + base + a2] = o2[1];
  out[(size_t)2 * 1000000 + base + a2] = o2[2];
  out[(size_t)3 * 1000000 + base + a2] = o2[3];
  if (has3) {
    out[(size_t)0 * 1000000 + base + a3] = o3[0];
    out[(size_t)1 * 1000000 + base + a3] = o3[1];
    out[(size_t)2 * 1000000 + base + a3] = o3[2];
    out[(size_t)3 * 1000000 + base + a3] = o3[3];
  }
}

extern "C" void kernel_launch(void* const* d_in, const int* in_sizes, int n_in,
                              void* d_out, int out_size, void* d_ws, size_t ws_size,
                              hipStream_t stream) {
  const float* xin  = (const float*)d_in[0];   // local_x  (1,4,1000,1000)
  const float* hist = (const float*)d_in[1];   // ms_history (1,16,4,1000,1000)
  float* out = (float*)d_out;
  float* AG  = (float*)d_ws;                   // 1600 * 256 floats = 1.6 MB

  k_gram_solve<<<NGX * NGY, 256, 0, stream>>>(xin, hist, AG);
  k_project  <<<NGX * NGY, 256, 0, stream>>>(hist, AG, out);
}

// Round 5
// 311.977 us; speedup vs baseline: 9.1600x; 1.2499x over previous
//
#include <hip/hip_runtime.h>

#define NGS 25
#define NGX 40
#define NGY 40
#define KK  64
#define NB2 4
#define NYY 1000
#define PTOT 625
#define PC  128
#define NCH 5
#define DAMP 0.01f

typedef __attribute__((ext_vector_type(8))) short short8;
typedef __attribute__((ext_vector_type(4))) float f32x4;

__device__ __forceinline__ short bf16_rn(float x) {
  unsigned u = __float_as_uint(x);
  u = u + 0x7fffu + ((u >> 16) & 1u);
  return (short)(u >> 16);
}
__device__ __forceinline__ float bf16_tof(short s) {
  return __uint_as_float(((unsigned)(unsigned short)s) << 16);
}

// ---------------- Kernel 1: MFMA Gram (bf16 hi/lo) + register Gauss-Jordan ---
__global__ __launch_bounds__(256, 4) void k_gram_solve(
    const float* __restrict__ xin, const float* __restrict__ hist,
    float* __restrict__ AG)
{
  __shared__ __align__(16) short smem[2 * 80 * 128];   // 40 KB
  short* Vhi = smem;
  short* Vlo = smem + 80 * 128;
  float (*Gs)[KK + 5] = (float (*)[KK + 5])smem;       // 64 x 69 fp32 (aliases planes)
  float* prow = ((float*)smem) + 4416;                 // 2 x 72 fp32 ping-pong pivot row

  const int tile = blockIdx.x;
  const int gx = tile / NGY, gy = tile % NGY;
  const size_t base = (size_t)(gx * NGS) * NYY + (size_t)(gy * NGS);
  const int tid  = threadIdx.x;
  const int wave = tid >> 6;
  const int lane = tid & 63;
  const int u    = lane >> 4;     // k-group 0..3
  const int col  = lane & 15;

  // per-thread constant staging coords: pp = tid&127 (constant over it), r = rb+2*it
  const int pp = tid & 127;
  const int rb = tid >> 7;

  // zero-pad rows 68..79 once
  for (int i = tid + 68 * 128; i < 80 * 128; i += 256) { Vhi[i] = 0; Vlo[i] = 0; }

  f32x4 accG[4];
  #pragma unroll
  for (int j = 0; j < 4; ++j) { accG[j].x = 0.f; accG[j].y = 0.f; accG[j].z = 0.f; accG[j].w = 0.f; }
  f32x4 accX; accX.x = 0.f; accX.y = 0.f; accX.z = 0.f; accX.w = 0.f;

  const int rA = 16 * wave + col;
  const int rX = KK + col;

  for (int ch = 0; ch < NCH; ++ch) {
    const int p = ch * PC + pp;
    const bool inb = (p < PTOT);
    const int px = p / NGS, py = p - px * NGS;
    const size_t a = base + (size_t)px * NYY + py;

    // ---- issue ALL 34 loads into registers (static unroll), then convert+write
    float vv[34];
    #pragma unroll
    for (int it = 0; it < 34; ++it) {
      const int r = rb + 2 * it;
      const float* srcp = (it < 32) ? (hist + (size_t)r * 1000000)
                                    : (xin + (size_t)(r - KK) * 1000000);
      vv[it] = inb ? srcp[a] : 0.f;
    }
    #pragma unroll
    for (int it = 0; it < 34; ++it) {
      const int r = rb + 2 * it;
      const short h = bf16_rn(vv[it]);
      const short l = bf16_rn(vv[it] - bf16_tof(h));
      const int off = r * 128 + ((((pp >> 3) ^ (r & 7)) << 3) | (pp & 7));
      Vhi[off] = h; Vlo[off] = l;
    }
    __syncthreads();

    // ---- 4 K-steps of 32 per chunk
    #pragma unroll
    for (int t = 0; t < 4; ++t) {
      const int k8 = t * 4 + u;
      #define FRG(P, r) (*(const short8*)&P[(r) * 128 + (((k8) ^ ((r) & 7)) << 3)])
      const short8 a_hi = FRG(Vhi, rA);
      const short8 a_lo = FRG(Vlo, rA);
      const short8 x_hi = FRG(Vhi, rX);
      const short8 x_lo = FRG(Vlo, rX);
      short8 b_hi[4], b_lo[4];
      #pragma unroll
      for (int s = 0; s < 4; ++s) {
        b_hi[s] = FRG(Vhi, 16 * s + col);
        b_lo[s] = FRG(Vlo, 16 * s + col);
      }
      #undef FRG
      #pragma unroll
      for (int j = 0; j < 4; ++j) {
        accG[j] = __builtin_amdgcn_mfma_f32_16x16x32_bf16(a_hi, b_hi[j], accG[j], 0, 0, 0);
        accG[j] = __builtin_amdgcn_mfma_f32_16x16x32_bf16(a_hi, b_lo[j], accG[j], 0, 0, 0);
        accG[j] = __builtin_amdgcn_mfma_f32_16x16x32_bf16(a_lo, b_hi[j], accG[j], 0, 0, 0);
      }
      accX = __builtin_amdgcn_mfma_f32_16x16x32_bf16(x_hi, a_hi, accX, 0, 0, 0);
      accX = __builtin_amdgcn_mfma_f32_16x16x32_bf16(x_hi, a_lo, accX, 0, 0, 0);
      accX = __builtin_amdgcn_mfma_f32_16x16x32_bf16(x_lo, a_hi, accX, 0, 0, 0);
    }
    __syncthreads();
  }

  // ---- write G (+damping) into Gs (aliases planes; all plane reads done)
  const int row4 = u * 4;
  #pragma unroll
  for (int j = 0; j < 4; ++j)
    #pragma unroll
    for (int q = 0; q < 4; ++q) {
      const int gr = 16 * wave + row4 + q;
      const int gc = 16 * j + col;
      float g = (q == 0) ? accG[j].x : (q == 1) ? accG[j].y : (q == 2) ? accG[j].z : accG[j].w;
      Gs[gr][gc] = g + ((gr == gc) ? DAMP : 0.f);
    }
  if (lane < 16) {
    Gs[16 * wave + lane][KK + 0] = accX.x;
    Gs[16 * wave + lane][KK + 1] = accX.y;
    Gs[16 * wave + lane][KK + 2] = accX.z;
    Gs[16 * wave + lane][KK + 3] = accX.w;
  }
  __syncthreads();

  // ---- register Gauss-Jordan: thread (ei,eq) owns cols {eq+4jj} of row ei ----
  const int ei = tid >> 2, eq = tid & 3;
  float v[17];
  #pragma unroll
  for (int jj = 0; jj < 17; ++jj) v[jj] = Gs[ei][4 * jj + eq];

  float myDiag = 1.f;
  if (ei == 0) {
    #pragma unroll
    for (int jj = 0; jj < 17; ++jj) prow[4 * jj + eq] = v[jj];
  }
  __syncthreads();

  #pragma unroll
  for (int k = 0; k < KK; ++k) {
    const float* pr = prow + (k & 1) * 72;
    const float piv = pr[k];
    const float num = __shfl(v[k >> 2], (lane & ~3) | (k & 3), 64);
    const float f = (ei == k) ? 0.f : (num / piv);
    if (ei == k) myDiag = piv;
    #pragma unroll
    for (int jj = (k < 3 ? 0 : (k - 2) >> 2); jj < 17; ++jj)
      v[jj] -= f * pr[4 * jj + eq];
    if (k < KK - 1) {
      if (ei == k + 1) {
        float* pw = prow + ((k + 1) & 1) * 72;
        #pragma unroll
        for (int jj = 0; jj < 17; ++jj) pw[4 * jj + eq] = v[jj];
      }
    }
    __syncthreads();
  }

  // Jordan leaves diag * x = rhs; rhs col (64+eq) sits at jj=16.
  AG[(size_t)tile * 256 + eq * 64 + ei] = v[16] / myDiag;
}

// ---------------- Kernel 2: Y = AG * V, scatter to output ---------------------
__global__ __launch_bounds__(256) void k_project(
    const float* __restrict__ hist, const float* __restrict__ AG,
    float* __restrict__ out)
{
  __shared__ float ag[KK][NB2];   // ag[k][c]
  const int tile = blockIdx.x;
  const int gx = tile / NGY, gy = tile % NGY;
  const size_t base = (size_t)(gx * NGS) * NYY + (size_t)(gy * NGS);
  const int tid = threadIdx.x;
  {
    const int c = tid >> 6, k = tid & 63;
    ag[k][c] = AG[(size_t)tile * 256 + tid];   // AG[c][k] -> ag[k][c]
  }
  __syncthreads();

  const int p1 = tid, p2 = tid + 256, p3 = tid + 512;
  const int a1 = (p1 / NGS) * NYY + (p1 % NGS);
  const int a2 = (p2 / NGS) * NYY + (p2 % NGS);
  const bool has3 = (p3 < PTOT);
  const int a3 = has3 ? ((p3 / NGS) * NYY + (p3 % NGS)) : 0;

  float o1[4] = {0,0,0,0}, o2[4] = {0,0,0,0}, o3[4] = {0,0,0,0};
  const float4* ag4 = (const float4*)ag;

  #pragma unroll 4
  for (int k = 0; k < KK; ++k) {
    const size_t ko = (size_t)k * 1000000 + base;
    const float v1 = hist[ko + a1];
    const float v2 = hist[ko + a2];
    const float v3 = has3 ? hist[ko + a3] : 0.f;
    const float4 w = ag4[k];
    o1[0] += w.x * v1; o1[1] += w.y * v1; o1[2] += w.z * v1; o1[3] += w.w * v1;
    o2[0] += w.x * v2; o2[1] += w.y * v2; o2[2] += w.z * v2; o2[3] += w.w * v2;
    o3[0] += w.x * v3; o3[1] += w.y * v3; o3[2] += w.z * v3; o3[3] += w.w * v3;
  }

  out[(size_t)0 * 1000000 + base + a1] = o1[0];
  out[(size_t)1 * 1000000 + base + a1] = o1[1];
  out[(size_t)2 * 1000000 + base + a1] = o1[2];
  out[(size_t)3 * 1000000 + base + a1] = o1[3];
  out[(size_t)0 * 1000000 + base + a2] = o2[0];
  out[(size_t)1 * 1000000 + base + a2] = o2[1];
  out[(size_t)2 * 1000000 + base + a2] = o2[2];
  out[(size_t)3 * 1000000 + base + a2] = o2[3];
  if (has3) {
    out[(size_t)0 * 1000000 + base + a3] = o3[0];
    out[(size_t)1 * 1000000 + base + a3] = o3[1];
    out[(size_t)2 * 1000000 + base + a3] = o3[2];
    out[(size_t)3 * 1000000 + base + a3] = o3[3];
  }
}

extern "C" void kernel_launch(void* const* d_in, const int* in_sizes, int n_in,
                              void* d_out, int out_size, void* d_ws, size_t ws_size,
                              hipStream_t stream) {
  const float* xin  = (const float*)d_in[0];   // local_x  (1,4,1000,1000)
  const float* hist = (const float*)d_in[1];   // ms_history (1,16,4,1000,1000)
  float* out = (float*)d_out;
  float* AG  = (float*)d_ws;                   // 1600 * 256 floats = 1.6 MB

  k_gram_solve<<<NGX * NGY, 256, 0, stream>>>(xin, hist, AG);
  k_project  <<<NGX * NGY, 256, 0, stream>>>(hist, AG, out);
}

// Round 6
// 219.849 us; speedup vs baseline: 12.9985x; 1.4190x over previous
//
#include <hip/hip_runtime.h>

#define NGS 25
#define NGX 40
#define NGY 40
#define KK  64
#define NB2 4
#define NYY 1000
#define PTOT 625
#define PC  128
#define NCH 5
#define DAMP 0.01f

typedef __attribute__((ext_vector_type(8))) short short8;
typedef __attribute__((ext_vector_type(4))) float f32x4;

__device__ __forceinline__ short bf16_rn(float x) {
  unsigned u = __float_as_uint(x);
  u = u + 0x7fffu + ((u >> 16) & 1u);
  return (short)(u >> 16);
}
__device__ __forceinline__ float bf16_tof(short s) {
  return __uint_as_float(((unsigned)(unsigned short)s) << 16);
}

// ---------------- Kernel 1: MFMA Gram (bf16 hi/lo) + register Gauss-Jordan ---
__global__ __launch_bounds__(256, 4) void k_gram_solve(
    const float* __restrict__ xin, const float* __restrict__ hist,
    float* __restrict__ AG)
{
  __shared__ __align__(16) short smem[2 * 80 * 128];   // 40 KB
  short* Vhi = smem;
  short* Vlo = smem + 80 * 128;
  float (*Gs)[KK + 5] = (float (*)[KK + 5])smem;       // 64 x 69 fp32 (aliases planes)
  float* prow = ((float*)smem) + 4416;                 // 2 x 72 fp32 ping-pong pivot row

  const int tile = blockIdx.x;
  const int gx = tile / NGY, gy = tile % NGY;
  const size_t base = (size_t)(gx * NGS) * NYY + (size_t)(gy * NGS);
  const int tid  = threadIdx.x;
  const int wave = tid >> 6;
  const int lane = tid & 63;
  const int u    = lane >> 4;     // k-group 0..3
  const int col  = lane & 15;

  // per-thread constant staging coords: pp = tid&127, row = rb + 2*it
  const int pp = tid & 127;
  const int rb = tid >> 7;

  // zero-pad rows 68..79 once
  for (int i = tid + 68 * 128; i < 80 * 128; i += 256) { Vhi[i] = 0; Vlo[i] = 0; }

  f32x4 accG[4];
  #pragma unroll
  for (int j = 0; j < 4; ++j) { accG[j].x = 0.f; accG[j].y = 0.f; accG[j].z = 0.f; accG[j].w = 0.f; }
  f32x4 accX; accX.x = 0.f; accX.y = 0.f; accX.z = 0.f; accX.w = 0.f;

  const int rA = 16 * wave + col;
  const int rX = KK + col;

  // truncation hi-split: h = top 16 bits, l = bf16_rn(residual). Residual term
  // still captured to bf16 precision; total rel err ~2^-16, far under threshold.
  #define STW(r, val) { \
    const short h = (short)(__float_as_uint(val) >> 16); \
    const short l = bf16_rn((val) - bf16_tof(h)); \
    const int off = (r) * 128 + ((((pp >> 3) ^ ((r) & 7)) << 3) | (pp & 7)); \
    Vhi[off] = h; Vlo[off] = l; }

  for (int ch = 0; ch < NCH; ++ch) {
    const int p = ch * PC + pp;
    const bool inb = (p < PTOT);
    const int px = p / NGS, py = p - px * NGS;
    const size_t a = base + (size_t)px * NYY + py;

    // ---- 3-batch interleaved prefetch: <=24 loads in flight, no spill
    float v0[12], v1[12], v2[10];
    #pragma unroll
    for (int it = 0; it < 12; ++it)
      v0[it] = inb ? hist[(size_t)(rb + 2 * it) * 1000000 + a] : 0.f;
    #pragma unroll
    for (int it = 0; it < 12; ++it)
      v1[it] = inb ? hist[(size_t)(rb + 2 * (it + 12)) * 1000000 + a] : 0.f;
    #pragma unroll
    for (int it = 0; it < 12; ++it) STW(rb + 2 * it, v0[it]);
    #pragma unroll
    for (int it = 0; it < 10; ++it) {
      const int r = rb + 2 * (it + 24);
      v2[it] = inb ? ((it < 8) ? hist[(size_t)r * 1000000 + a]
                               : xin[(size_t)(r - KK) * 1000000 + a]) : 0.f;
    }
    #pragma unroll
    for (int it = 0; it < 12; ++it) STW(rb + 2 * (it + 12), v1[it]);
    #pragma unroll
    for (int it = 0; it < 10; ++it) STW(rb + 2 * (it + 24), v2[it]);
    __syncthreads();

    // ---- 4 K-steps of 32 per chunk
    #pragma unroll
    for (int t = 0; t < 4; ++t) {
      const int k8 = t * 4 + u;
      #define FRG(P, r) (*(const short8*)&P[(r) * 128 + (((k8) ^ ((r) & 7)) << 3)])
      const short8 a_hi = FRG(Vhi, rA);
      const short8 a_lo = FRG(Vlo, rA);
      const short8 x_hi = FRG(Vhi, rX);
      const short8 x_lo = FRG(Vlo, rX);
      short8 b_hi[4], b_lo[4];
      #pragma unroll
      for (int s = 0; s < 4; ++s) {
        b_hi[s] = FRG(Vhi, 16 * s + col);
        b_lo[s] = FRG(Vlo, 16 * s + col);
      }
      #undef FRG
      #pragma unroll
      for (int j = 0; j < 4; ++j) {
        accG[j] = __builtin_amdgcn_mfma_f32_16x16x32_bf16(a_hi, b_hi[j], accG[j], 0, 0, 0);
        accG[j] = __builtin_amdgcn_mfma_f32_16x16x32_bf16(a_hi, b_lo[j], accG[j], 0, 0, 0);
        accG[j] = __builtin_amdgcn_mfma_f32_16x16x32_bf16(a_lo, b_hi[j], accG[j], 0, 0, 0);
      }
      accX = __builtin_amdgcn_mfma_f32_16x16x32_bf16(x_hi, a_hi, accX, 0, 0, 0);
      accX = __builtin_amdgcn_mfma_f32_16x16x32_bf16(x_hi, a_lo, accX, 0, 0, 0);
      accX = __builtin_amdgcn_mfma_f32_16x16x32_bf16(x_lo, a_hi, accX, 0, 0, 0);
    }
    __syncthreads();
  }
  #undef STW

  // ---- write G (+damping) into Gs (aliases planes; all plane reads done)
  const int row4 = u * 4;
  #pragma unroll
  for (int j = 0; j < 4; ++j)
    #pragma unroll
    for (int q = 0; q < 4; ++q) {
      const int gr = 16 * wave + row4 + q;
      const int gc = 16 * j + col;
      float g = (q == 0) ? accG[j].x : (q == 1) ? accG[j].y : (q == 2) ? accG[j].z : accG[j].w;
      Gs[gr][gc] = g + ((gr == gc) ? DAMP : 0.f);
    }
  if (lane < 16) {
    Gs[16 * wave + lane][KK + 0] = accX.x;
    Gs[16 * wave + lane][KK + 1] = accX.y;
    Gs[16 * wave + lane][KK + 2] = accX.z;
    Gs[16 * wave + lane][KK + 3] = accX.w;
  }
  __syncthreads();

  // ---- register Gauss-Jordan: thread (ei,eq) owns cols {eq+4jj} of row ei ----
  const int ei = tid >> 2, eq = tid & 3;
  float v[17];
  #pragma unroll
  for (int jj = 0; jj < 17; ++jj) v[jj] = Gs[ei][4 * jj + eq];

  float myDiag = 1.f;
  if (ei == 0) {
    #pragma unroll
    for (int jj = 0; jj < 17; ++jj) prow[4 * jj + eq] = v[jj];
  }
  __syncthreads();

  #pragma unroll
  for (int k = 0; k < KK; ++k) {
    const float* pr = prow + (k & 1) * 72;
    const float piv = pr[k];
    const float num = __shfl(v[k >> 2], (lane & ~3) | (k & 3), 64);
    const float f = (ei == k) ? 0.f : (num / piv);
    if (ei == k) myDiag = piv;
    #pragma unroll
    for (int jj = (k < 3 ? 0 : (k - 2) >> 2); jj < 17; ++jj)
      v[jj] -= f * pr[4 * jj + eq];
    if (k < KK - 1) {
      if (ei == k + 1) {
        float* pw = prow + ((k + 1) & 1) * 72;
        #pragma unroll
        for (int jj = 0; jj < 17; ++jj) pw[4 * jj + eq] = v[jj];
      }
    }
    __syncthreads();
  }

  // Jordan leaves diag * x = rhs; rhs col (64+eq) sits at jj=16.
  AG[(size_t)tile * 256 + eq * 64 + ei] = v[16] / myDiag;
}

// ---------------- Kernel 2: Y = AG * V, scatter to output ---------------------
__global__ __launch_bounds__(256) void k_project(
    const float* __restrict__ hist, const float* __restrict__ AG,
    float* __restrict__ out)
{
  __shared__ float ag[KK][NB2];   // ag[k][c]
  const int tile = blockIdx.x;
  const int gx = tile / NGY, gy = tile % NGY;
  const size_t base = (size_t)(gx * NGS) * NYY + (size_t)(gy * NGS);
  const int tid = threadIdx.x;
  {
    const int c = tid >> 6, k = tid & 63;
    ag[k][c] = AG[(size_t)tile * 256 + tid];   // AG[c][k] -> ag[k][c]
  }
  __syncthreads();

  const int p1 = tid, p2 = tid + 256, p3 = tid + 512;
  const int a1 = (p1 / NGS) * NYY + (p1 % NGS);
  const int a2 = (p2 / NGS) * NYY + (p2 % NGS);
  const bool has3 = (p3 < PTOT);
  const int a3 = has3 ? ((p3 / NGS) * NYY + (p3 % NGS)) : 0;

  float o1[4] = {0,0,0,0}, o2[4] = {0,0,0,0}, o3[4] = {0,0,0,0};
  const float4* ag4 = (const float4*)ag;

  #pragma unroll 4
  for (int k = 0; k < KK; ++k) {
    const size_t ko = (size_t)k * 1000000 + base;
    const float v1 = hist[ko + a1];
    const float v2 = hist[ko + a2];
    const float v3 = has3 ? hist[ko + a3] : 0.f;
    const float4 w = ag4[k];
    o1[0] += w.x * v1; o1[1] += w.y * v1; o1[2] += w.z * v1; o1[3] += w.w * v1;
    o2[0] += w.x * v2; o2[1] += w.y * v2; o2[2] += w.z * v2; o2[3] += w.w * v2;
    o3[0] += w.x * v3; o3[1] += w.y * v3; o3[2] += w.z * v3; o3[3] += w.w * v3;
  }

  out[(size_t)0 * 1000000 + base + a1] = o1[0];
  out[(size_t)1 * 1000000 + base + a1] = o1[1];
  out[(size_t)2 * 1000000 + base + a1] = o1[2];
  out[(size_t)3 * 1000000 + base + a1] = o1[3];
  out[(size_t)0 * 1000000 + base + a2] = o2[0];
  out[(size_t)1 * 1000000 + base + a2] = o2[1];
  out[(size_t)2 * 1000000 + base + a2] = o2[2];
  out[(size_t)3 * 1000000 + base + a2] = o2[3];
  if (has3) {
    out[(size_t)0 * 1000000 + base + a3] = o3[0];
    out[(size_t)1 * 1000000 + base + a3] = o3[1];
    out[(size_t)2 * 1000000 + base + a3] = o3[2];
    out[(size_t)3 * 1000000 + base + a3] = o3[3];
  }
}

extern "C" void kernel_launch(void* const* d_in, const int* in_sizes, int n_in,
                              void* d_out, int out_size, void* d_ws, size_t ws_size,
                              hipStream_t stream) {
  const float* xin  = (const float*)d_in[0];   // local_x  (1,4,1000,1000)
  const float* hist = (const float*)d_in[1];   // ms_history (1,16,4,1000,1000)
  float* out = (float*)d_out;
  float* AG  = (float*)d_ws;                   // 1600 * 256 floats = 1.6 MB

  k_gram_solve<<<NGX * NGY, 256, 0, stream>>>(xin, hist, AG);
  k_project  <<<NGX * NGY, 256, 0, stream>>>(hist, AG, out);
}